// Round 5
// baseline (199.407 us; speedup 1.0000x reference)
//
#include <hip/hip_runtime.h>

#define NN 50000      // N_ENT
#define NR 100        // N_REL2
#define NB 16         // N_BASES
#define D  64         // DIM
#define NE 100000     // N_EDGES
#define NE2 (NE + 512)               // padded edge array capacity

#define HB  196       // histogram/scatter blocks
#define EPB 512       // edges per block in hist/scatter

#define CHUNK 112     // edges per edge-kernel block (4 waves x 28)
#define EGRID 1024    // max chunks (>= NE_padded/112 + NR)

#define NPB 128       // nodes per node-kernel block (4 waves x 32)
#define NGRID ((NN + NPB - 1) / NPB)

typedef float f32x4 __attribute__((ext_vector_type(4)));

// Fused weight prep. Blocks 0..199: Wt[layer][r][d][k] = sum_b att[r,b]*basis[b,k,d]
// (transposed via padded-LDS). Blocks 200..201: rT[d][k] = root[k][d].
__global__ __launch_bounds__(256) void compute_wt(
    const float* __restrict__ att1, const float* __restrict__ basis1,
    const float* __restrict__ root1,
    const float* __restrict__ att2, const float* __restrict__ basis2,
    const float* __restrict__ root2,
    float* __restrict__ Wt1, float* __restrict__ Wt2,
    float* __restrict__ rT1, float* __restrict__ rT2)
{
    __shared__ float t[64 * 65];
    int b = blockIdx.x;
    if (b < 2 * NR) {
        int layer = b >= NR;
        int r = layer ? b - NR : b;
        const float* att   = layer ? att2 : att1;
        const float* basis = layer ? basis2 : basis1;
        float*       Wt    = layer ? Wt2 : Wt1;
        float a[NB];
#pragma unroll
        for (int bb = 0; bb < NB; ++bb) a[bb] = att[r * NB + bb];
#pragma unroll
        for (int i = 0; i < 16; ++i) {
            int idx = i * 256 + threadIdx.x;        // [k][d] linear
            float acc = 0.f;
#pragma unroll
            for (int bb = 0; bb < NB; ++bb) acc += a[bb] * basis[bb * 4096 + idx];
            t[(idx >> 6) * 65 + (idx & 63)] = acc;  // t[k][d], padded
        }
        __syncthreads();
#pragma unroll
        for (int i = 0; i < 16; ++i) {
            int j = i * 256 + threadIdx.x;          // [d][k] linear
            Wt[(size_t)r * 4096 + j] = t[(j & 63) * 65 + (j >> 6)];
        }
    } else {
        const float* root = (b == 2 * NR) ? root1 : root2;
        float*       rT   = (b == 2 * NR) ? rT1 : rT2;
#pragma unroll
        for (int i = 0; i < 16; ++i) {
            int idx = i * 256 + threadIdx.x;
            t[(idx >> 6) * 65 + (idx & 63)] = root[idx];
        }
        __syncthreads();
#pragma unroll
        for (int i = 0; i < 16; ++i) {
            int j = i * 256 + threadIdx.x;
            rT[j] = t[(j & 63) * 65 + (j >> 6)];
        }
    }
}

// x0[n, :] = emb[entity[n], :]  (float4 vectorized)
__global__ __launch_bounds__(256) void gather_emb(
    const int* __restrict__ entity, const f32x4* __restrict__ emb4,
    f32x4* __restrict__ x04)
{
    int idx = blockIdx.x * 256 + threadIdx.x;      // over NN*16
    if (idx >= NN * 16) return;
    int n = idx >> 4;
    int q = idx & 15;
    x04[idx] = emb4[(size_t)entity[n] * 16 + q];
}

// Pass 1: per-block relation histogram (LDS atomics) + node in-degree
__global__ __launch_bounds__(256) void hist_edges(
    const int* __restrict__ et, const int* __restrict__ dst,
    int* __restrict__ blockHist, float* __restrict__ cnt)
{
    __shared__ int lh[NR];
    for (int i = threadIdx.x; i < NR; i += 256) lh[i] = 0;
    __syncthreads();
#pragma unroll
    for (int i = 0; i < EPB / 256; ++i) {
        int e = blockIdx.x * EPB + i * 256 + threadIdx.x;
        if (e < NE) {
            atomicAdd(&lh[et[e]], 1);
            atomicAdd(&cnt[dst[e]], 1.0f);
        }
    }
    __syncthreads();
    for (int i = threadIdx.x; i < NR; i += 256)
        blockHist[blockIdx.x * NR + i] = lh[i];
}

// Pass 2: padded (4-aligned) segment offsets, per-(block,rel) scatter bases,
// block table (relation, chunkStart), and dummy-edge gap fill.
__global__ void scan_blocks(const int* __restrict__ blockHist,
                            int* __restrict__ blockBase, int* __restrict__ offsP,
                            int* __restrict__ tabR, int* __restrict__ tabS,
                            int* __restrict__ nbG,
                            int* __restrict__ srcS, int* __restrict__ dstS,
                            float* __restrict__ normS)
{
    __shared__ int totL[NR];
    __shared__ int offL[NR + 1];
    int r = threadIdx.x;             // 128 threads
    if (r < NR) {
        int tot = 0;
        for (int b = 0; b < HB; ++b) tot += blockHist[b * NR + r];
        totL[r] = tot;
    }
    __syncthreads();
    if (r == 0) {
        int cur = 0;
        for (int i = 0; i < NR; ++i) {
            offL[i] = cur;
            cur = (cur + totL[i] + 3) & ~3;     // 4-aligned padded segments
        }
        offL[NR] = cur;
        int nb = 0;
        for (int i = 0; i < NR; ++i)
            for (int c = offL[i]; c < offL[i + 1]; c += CHUNK) {
                tabR[nb] = i; tabS[nb] = c; ++nb;
            }
        nbG[0] = nb;
    }
    __syncthreads();
    if (r < NR) {
        int acc = offL[r];
        for (int b = 0; b < HB; ++b) {
            blockBase[b * NR + r] = acc;
            acc += blockHist[b * NR + r];
        }
        // gap fill with dummy edges (norm=0 -> contributes +0.0 to s[0])
        for (int p = acc; p < offL[r + 1]; ++p) {
            srcS[p] = 0; dstS[p] = 0; normS[p] = 0.f;
        }
        offsP[r] = offL[r];
        if (r == 0) offsP[NR] = offL[NR];
    }
}

// Pass 3: scatter edges into relation-sorted arrays (LDS cursors only)
__global__ __launch_bounds__(256) void scatter_sorted(
    const int* __restrict__ src, const int* __restrict__ dst,
    const int* __restrict__ et, const float* __restrict__ en,
    const int* __restrict__ blockBase, int* __restrict__ srcS,
    int* __restrict__ dstS, float* __restrict__ normS)
{
    __shared__ int lcur[NR];
    for (int i = threadIdx.x; i < NR; i += 256)
        lcur[i] = blockBase[blockIdx.x * NR + i];
    __syncthreads();
#pragma unroll
    for (int i = 0; i < EPB / 256; ++i) {
        int e = blockIdx.x * EPB + i * 256 + threadIdx.x;
        if (e < NE) {
            int r = et[e];
            int p = atomicAdd(&lcur[r], 1);
            srcS[p] = src[e]; dstS[p] = dst[e]; normS[p] = en[e];
        }
    }
}

// Edge kernel: one block per (relation, 112-edge chunk). W[r] staged in LDS
// once per block with XOR bank swizzle; 4-edge unroll shares each ds_read_b128
// across 4 edges' FMAs. x-row broadcast via v_readlane.
__global__ __launch_bounds__(256, 4) void edge_lds(
    const int* __restrict__ srcS, const int* __restrict__ dstS,
    const float* __restrict__ normS, const int* __restrict__ offsP,
    const int* __restrict__ tabR, const int* __restrict__ tabS,
    const int* __restrict__ nbG, const float* __restrict__ x,
    const float* __restrict__ Wt, float* __restrict__ s)
{
    __shared__ f32x4 WL4[1024];                    // 16 KB
    int b = blockIdx.x;
    if (b >= nbG[0]) return;
    int r  = tabR[b];
    int cs = tabS[b];
    int tid = threadIdx.x;

    // stage Wt[r] (d-major rows) with slot swizzle: slot = g ^ (d&7)
    {
        const f32x4* __restrict__ Wg = (const f32x4*)(Wt + (size_t)r * 4096);
#pragma unroll
        for (int i = 0; i < 4; ++i) {
            int idx = tid + i * 256;               // f32x4 index 0..1023
            f32x4 v = Wg[idx];
            int d = idx >> 4, g = idx & 15;
            *(f32x4*)((char*)WL4 + ((d << 8) | ((g ^ (d & 7)) << 4))) = v;
        }
    }
    __syncthreads();

    int wid  = tid >> 6;
    int lane = tid & 63;
    int wstart = cs + wid * 28;
    int wend   = cs + CHUNK;
    int segE   = offsP[r + 1];
    if (segE < wend) wend = segE;
    int cw = wend - wstart;
    if (cw <= 0) return;
    if (cw > 28) cw = 28;                          // multiple of 4, >= 4

    int ei   = wstart + (lane < cw ? lane : 0);    // lane i holds meta of edge wstart+i
    int srcv = srcS[ei];
    int dstv = dstS[ei];
    int nrmv = __float_as_int(normS[ei]);

    const int base = (lane << 8) | ((lane & 7) << 4);

    float xv0 = x[(size_t)__builtin_amdgcn_readlane(srcv, 0) * 64 + lane];
    float xv1 = x[(size_t)__builtin_amdgcn_readlane(srcv, 1) * 64 + lane];
    float xv2 = x[(size_t)__builtin_amdgcn_readlane(srcv, 2) * 64 + lane];
    float xv3 = x[(size_t)__builtin_amdgcn_readlane(srcv, 3) * 64 + lane];

    for (int g0 = 0; g0 < cw; g0 += 4) {
        int xc[4];
        xc[0] = __float_as_int(xv0); xc[1] = __float_as_int(xv1);
        xc[2] = __float_as_int(xv2); xc[3] = __float_as_int(xv3);
        int dn[4]; float nm[4];
#pragma unroll
        for (int j = 0; j < 4; ++j) {
            dn[j] = __builtin_amdgcn_readlane(dstv, g0 + j);
            nm[j] = __int_as_float(__builtin_amdgcn_readlane(nrmv, g0 + j));
        }
        if (g0 + 4 < cw) {
            xv0 = x[(size_t)__builtin_amdgcn_readlane(srcv, g0 + 4) * 64 + lane];
            xv1 = x[(size_t)__builtin_amdgcn_readlane(srcv, g0 + 5) * 64 + lane];
            xv2 = x[(size_t)__builtin_amdgcn_readlane(srcv, g0 + 6) * 64 + lane];
            xv3 = x[(size_t)__builtin_amdgcn_readlane(srcv, g0 + 7) * 64 + lane];
        }
        float a[4][4] = {{0.f}};
#pragma unroll
        for (int t = 0; t < 16; ++t) {
            f32x4 ww = *(const f32x4*)((const char*)WL4 + (base ^ (t << 4)));
#pragma unroll
            for (int j = 0; j < 4; ++j) {
                a[j][0] = fmaf(__int_as_float(__builtin_amdgcn_readlane(xc[j], 4 * t + 0)), ww.x, a[j][0]);
                a[j][1] = fmaf(__int_as_float(__builtin_amdgcn_readlane(xc[j], 4 * t + 1)), ww.y, a[j][1]);
                a[j][2] = fmaf(__int_as_float(__builtin_amdgcn_readlane(xc[j], 4 * t + 2)), ww.z, a[j][2]);
                a[j][3] = fmaf(__int_as_float(__builtin_amdgcn_readlane(xc[j], 4 * t + 3)), ww.w, a[j][3]);
            }
        }
#pragma unroll
        for (int j = 0; j < 4; ++j)
            atomicAdd(&s[(size_t)dn[j] * 64 + lane],
                      ((a[j][0] + a[j][1]) + (a[j][2] + a[j][3])) * nm[j]);
    }
}

// Node kernel: rT staged in LDS (same swizzle), 4-node unroll.
// In-place-safe (x == out): each wave writes only rows it already read.
__global__ __launch_bounds__(256, 4) void node_lds(
    const float* __restrict__ x, float* __restrict__ s,
    const float* __restrict__ cnt, const float* __restrict__ rT,
    const float* __restrict__ bias, float* __restrict__ out, int zero_s)
{
    __shared__ f32x4 RL4[1024];                    // 16 KB
    int tid = threadIdx.x;
    {
        const f32x4* __restrict__ Rg = (const f32x4*)rT;
#pragma unroll
        for (int i = 0; i < 4; ++i) {
            int idx = tid + i * 256;
            f32x4 v = Rg[idx];
            int d = idx >> 4, g = idx & 15;
            *(f32x4*)((char*)RL4 + ((d << 8) | ((g ^ (d & 7)) << 4))) = v;
        }
    }
    __syncthreads();

    int wid  = tid >> 6;
    int lane = tid & 63;
    int n0 = blockIdx.x * NPB + wid * 32;
    if (n0 >= NN) return;
    int n1 = n0 + 32 <= NN ? n0 + 32 : NN;         // count stays multiple of 4

    const int base = (lane << 8) | ((lane & 7) << 4);
    float bv = bias[lane];

    for (int n = n0; n < n1; n += 4) {
        int xc[4]; float sv[4], cv[4];
#pragma unroll
        for (int j = 0; j < 4; ++j) {
            xc[j] = __float_as_int(x[(size_t)(n + j) * 64 + lane]);
            sv[j] = s[(size_t)(n + j) * 64 + lane];
            cv[j] = cnt[n + j];
        }
        float a[4][4] = {{0.f}};
#pragma unroll
        for (int t = 0; t < 16; ++t) {
            f32x4 ww = *(const f32x4*)((const char*)RL4 + (base ^ (t << 4)));
#pragma unroll
            for (int j = 0; j < 4; ++j) {
                a[j][0] = fmaf(__int_as_float(__builtin_amdgcn_readlane(xc[j], 4 * t + 0)), ww.x, a[j][0]);
                a[j][1] = fmaf(__int_as_float(__builtin_amdgcn_readlane(xc[j], 4 * t + 1)), ww.y, a[j][1]);
                a[j][2] = fmaf(__int_as_float(__builtin_amdgcn_readlane(xc[j], 4 * t + 2)), ww.z, a[j][2]);
                a[j][3] = fmaf(__int_as_float(__builtin_amdgcn_readlane(xc[j], 4 * t + 3)), ww.w, a[j][3]);
            }
        }
#pragma unroll
        for (int j = 0; j < 4; ++j) {
            float c = cv[j] > 1.f ? cv[j] : 1.f;
            out[(size_t)(n + j) * 64 + lane] =
                sv[j] / c + ((a[j][0] + a[j][1]) + (a[j][2] + a[j][3])) + bv;
            if (zero_s) s[(size_t)(n + j) * 64 + lane] = 0.f;
        }
    }
}

extern "C" void kernel_launch(void* const* d_in, const int* in_sizes, int n_in,
                              void* d_out, int out_size, void* d_ws, size_t ws_size,
                              hipStream_t stream) {
    const int*   entity    = (const int*)d_in[0];
    const int*   edge_index= (const int*)d_in[1];    // [2, NE]
    const int*   edge_type = (const int*)d_in[2];
    const float* edge_norm = (const float*)d_in[3];
    const float* emb       = (const float*)d_in[4];
    const float* basis1    = (const float*)d_in[5];
    const float* att1      = (const float*)d_in[6];
    const float* root1     = (const float*)d_in[7];
    const float* bias1     = (const float*)d_in[8];
    const float* basis2    = (const float*)d_in[9];
    const float* att2      = (const float*)d_in[10];
    const float* root2     = (const float*)d_in[11];
    const float* bias2     = (const float*)d_in[12];

    const int* src = edge_index;
    const int* dst = edge_index + NE;

    // float arrays first (16B alignment for f32x4 loads), ints at the end
    float* ws    = (float*)d_ws;
    float* Wt1   = ws;                           // NR*4096
    float* Wt2   = Wt1 + (size_t)NR * 4096;      // NR*4096
    float* rT1   = Wt2 + (size_t)NR * 4096;      // 4096
    float* rT2   = rT1 + 4096;                   // 4096
    float* x0    = rT2 + 4096;                   // NN*D
    float* s     = x0  + (size_t)NN * D;         // NN*D
    float* cnt   = s   + (size_t)NN * D;         // NN
    float* normS = cnt + NN;                     // NE2
    int*   offsP     = (int*)(normS + NE2);      // NR+1
    int*   nbG       = offsP + NR + 1;           // 1 (+pad)
    int*   blockHist = nbG + 3;                  // HB*NR
    int*   blockBase = blockHist + HB * NR;      // HB*NR
    int*   tabR      = blockBase + HB * NR;      // EGRID
    int*   tabS      = tabR + EGRID;             // EGRID
    int*   srcS      = tabS + EGRID;             // NE2
    int*   dstS      = srcS + NE2;               // NE2

    float* out = (float*)d_out;

    // zero s + cnt (contiguous)
    hipMemsetAsync(s, 0, ((size_t)NN * D + NN) * sizeof(float), stream);

    compute_wt<<<2 * NR + 2, 256, 0, stream>>>(att1, basis1, root1,
                                               att2, basis2, root2,
                                               Wt1, Wt2, rT1, rT2);
    gather_emb<<<(NN * 16 + 255) / 256, 256, 0, stream>>>(
        entity, (const f32x4*)emb, (f32x4*)x0);
    hist_edges<<<HB, 256, 0, stream>>>(edge_type, dst, blockHist, cnt);
    scan_blocks<<<1, 128, 0, stream>>>(blockHist, blockBase, offsP,
                                       tabR, tabS, nbG, srcS, dstS, normS);
    scatter_sorted<<<HB, 256, 0, stream>>>(src, dst, edge_type, edge_norm,
                                           blockBase, srcS, dstS, normS);

    // ---- layer 1 ----
    edge_lds<<<EGRID, 256, 0, stream>>>(srcS, dstS, normS, offsP,
                                        tabR, tabS, nbG, x0, Wt1, s);
    node_lds<<<NGRID, 256, 0, stream>>>(x0, s, cnt, rT1, bias1, out, 1);

    // ---- layer 2 ----
    edge_lds<<<EGRID, 256, 0, stream>>>(srcS, dstS, normS, offsP,
                                        tabR, tabS, nbG, out, Wt2, s);
    node_lds<<<NGRID, 256, 0, stream>>>(out, s, cnt, rT2, bias2, out, 0);
}